// Round 2
// baseline (8829.482 us; speedup 1.0000x reference)
//
#include <hip/hip_runtime.h>
#include <hip/hip_bf16.h>

#define NUM_OPS   100000
#define NUM_MACH  512
#define HDIM      128

// ---------------- embedding: out[r,h] = sum_f F[r,f]*W[h,f] + b[h] ----------------
__global__ void k_embed(const float* __restrict__ F,
                        const float* __restrict__ W,
                        const float* __restrict__ b,
                        float* __restrict__ out, int M, int FD) {
    int idx = blockIdx.x * blockDim.x + threadIdx.x;
    if (idx >= M * HDIM) return;
    int r = idx >> 7, h = idx & 127;
    const float* f = F + (size_t)r * FD;
    const float* w = W + (size_t)h * FD;
    float s = b[h];
    for (int i = 0; i < FD; ++i) s += f[i] * w[i];
    out[idx] = s;
}

// ---------------- edge counts ----------------
__global__ void k_count_prec(const int* __restrict__ tgt, int n, float* __restrict__ cnt) {
    int e = blockIdx.x * blockDim.x + threadIdx.x;
    if (e < n) atomicAdd(&cnt[tgt[e]], 1.0f);
}

__global__ void k_count_compat(const int* __restrict__ edges, int n, int num_ops,
                               float* __restrict__ op_cnt, float* __restrict__ mach_cnt) {
    __shared__ float mc[NUM_MACH];
    for (int i = threadIdx.x; i < NUM_MACH; i += blockDim.x) mc[i] = 0.f;
    __syncthreads();
    for (int e = blockIdx.x * blockDim.x + threadIdx.x; e < n; e += gridDim.x * blockDim.x) {
        int s = edges[e], t = edges[n + e];
        if (s < num_ops && t >= num_ops) atomicAdd(&mc[t - num_ops], 1.0f);
        else if (s >= num_ops && t < num_ops) atomicAdd(&op_cnt[t], 1.0f);
    }
    __syncthreads();
    for (int i = threadIdx.x; i < NUM_MACH; i += blockDim.x)
        if (mc[i] != 0.f) atomicAdd(&mach_cnt[i], mc[i]);
}

// in-place x -> 1/max(x,1)
__global__ void k_inv(float* __restrict__ x, int n) {
    int i = blockIdx.x * blockDim.x + threadIdx.x;
    if (i < n) x[i] = 1.0f / fmaxf(x[i], 1.0f);
}

// ---------------- fused dual GEMM: Y[m, 0:128]=X@Wa^T+ba, Y[m,128:256]=X@Wb^T+bb ----------------
#define BM 64
#define BN 64
#define BK 16
__global__ __launch_bounds__(256) void k_gemm_dual(
    const float* __restrict__ X, int M,
    const float* __restrict__ Wa, const float* __restrict__ ba,
    const float* __restrict__ Wb, const float* __restrict__ bb,
    float* __restrict__ Y) {
    __shared__ float As[BK][BM + 4];
    __shared__ float Bs[BK][BN + 4];
    int by = blockIdx.y;
    int m0 = blockIdx.x * BM;
    const float* W; const float* bias; int n0;
    if (by < 2) { W = Wa; bias = ba; n0 = by * 64; }
    else        { W = Wb; bias = bb; n0 = (by - 2) * 64; }
    int colbase = (by < 2 ? 0 : 128) + n0;

    int t  = threadIdx.x;
    int tx = t & 15, ty = t >> 4;
    float acc[4][4] = {};

    for (int k0 = 0; k0 < HDIM; k0 += BK) {
        {   // A tile (transposed store)
            int m = t >> 2, k = (t & 3) * 4;
            int gm = m0 + m;
            float4 v = make_float4(0.f, 0.f, 0.f, 0.f);
            if (gm < M) v = *(const float4*)(X + (size_t)gm * HDIM + k0 + k);
            As[k + 0][m] = v.x; As[k + 1][m] = v.y; As[k + 2][m] = v.z; As[k + 3][m] = v.w;
        }
        {   // B tile (transposed store)
            int n = t >> 2, k = (t & 3) * 4;
            float4 v = *(const float4*)(W + (size_t)(n0 + n) * HDIM + k0 + k);
            Bs[k + 0][n] = v.x; Bs[k + 1][n] = v.y; Bs[k + 2][n] = v.z; Bs[k + 3][n] = v.w;
        }
        __syncthreads();
#pragma unroll
        for (int kk = 0; kk < BK; ++kk) {
            const float4 a = *(const float4*)&As[kk][ty * 4];
            const float4 b = *(const float4*)&Bs[kk][tx * 4];
            acc[0][0] += a.x * b.x; acc[0][1] += a.x * b.y; acc[0][2] += a.x * b.z; acc[0][3] += a.x * b.w;
            acc[1][0] += a.y * b.x; acc[1][1] += a.y * b.y; acc[1][2] += a.y * b.z; acc[1][3] += a.y * b.w;
            acc[2][0] += a.z * b.x; acc[2][1] += a.z * b.y; acc[2][2] += a.z * b.z; acc[2][3] += a.z * b.w;
            acc[3][0] += a.w * b.x; acc[3][1] += a.w * b.y; acc[3][2] += a.w * b.z; acc[3][3] += a.w * b.w;
        }
        __syncthreads();
    }
    float bx = bias[n0 + tx * 4 + 0];
    float by2 = bias[n0 + tx * 4 + 1];
    float bz = bias[n0 + tx * 4 + 2];
    float bw = bias[n0 + tx * 4 + 3];
#pragma unroll
    for (int i = 0; i < 4; ++i) {
        int gm = m0 + ty * 4 + i;
        if (gm < M) {
            float4 o = make_float4(acc[i][0] + bx, acc[i][1] + by2, acc[i][2] + bz, acc[i][3] + bw);
            *(float4*)(Y + (size_t)gm * 256 + colbase + tx * 4) = o;
        }
    }
}

// ---------------- machine linear: Y = X @ W^T + b  (M small) ----------------
__global__ __launch_bounds__(128) void k_mach_linear(
    const float* __restrict__ X, const float* __restrict__ W,
    const float* __restrict__ b, float* __restrict__ Y) {
    __shared__ float row[HDIM];
    int r = blockIdx.x, t = threadIdx.x;
    row[t] = X[(size_t)r * HDIM + t];
    __syncthreads();
    const float* w = W + (size_t)t * HDIM;
    float s = b[t];
#pragma unroll 8
    for (int k = 0; k < HDIM; ++k) s += row[k] * w[k];
    Y[(size_t)r * HDIM + t] = s;
}

// ---------------- prec scatter (pre-scaled): comb[t] += op_t[s] * inv[t] ----------------
__global__ void k_scatter_prec(const int* __restrict__ edges, int n,
                               const float* __restrict__ op_tc,
                               const float* __restrict__ inv,
                               float* __restrict__ comb) {
    int idx = blockIdx.x * blockDim.x + threadIdx.x;
    if (idx >= n * 32) return;
    int e = idx >> 5, q = idx & 31;
    int s = edges[e], t = edges[n + e];
    float iv = inv[t];
    float4 v = *(const float4*)(op_tc + (size_t)s * 256 + q * 4);
    float* dst = comb + (size_t)t * HDIM + q * 4;
    atomicAdd(dst + 0, v.x * iv); atomicAdd(dst + 1, v.y * iv);
    atomicAdd(dst + 2, v.z * iv); atomicAdd(dst + 3, v.w * iv);
}

// ---------------- compat op->mach scatter, LDS-staged (512 targets) ----------------
#define MS_H 16
__global__ __launch_bounds__(256) void k_scatter_comp_mach(
    const int* __restrict__ edges, int n, int num_ops,
    const float* __restrict__ op_tc, float* __restrict__ mach_sum) {
    __shared__ float acc[NUM_MACH * MS_H];
    for (int i = threadIdx.x; i < NUM_MACH * MS_H; i += 256) acc[i] = 0.f;
    __syncthreads();
    int h0 = blockIdx.y * MS_H;
    int per = (n + gridDim.x - 1) / gridDim.x;
    int e0 = blockIdx.x * per;
    int e1 = min(n, e0 + per);
    int hL = threadIdx.x & (MS_H - 1);
    int eo = threadIdx.x / MS_H;
    for (int e = e0 + eo; e < e1; e += 256 / MS_H) {
        int s = edges[e], t = edges[n + e];
        if (s < num_ops && t >= num_ops) {
            float v = op_tc[(size_t)s * 256 + 128 + h0 + hL];
            atomicAdd(&acc[(t - num_ops) * MS_H + hL], v);
        }
    }
    __syncthreads();
    for (int i = threadIdx.x; i < NUM_MACH * MS_H; i += 256) {
        float v = acc[i];
        if (v != 0.f) atomicAdd(&mach_sum[(size_t)(i / MS_H) * HDIM + h0 + (i & (MS_H - 1))], v);
    }
}

// ---------------- compat mach->op scatter (pre-scaled): comb[t] += mach_c[s] * inv[t] ----------------
__global__ void k_scatter_comp_op(const int* __restrict__ edges, int n, int num_ops,
                                  const float* __restrict__ mach_c,
                                  const float* __restrict__ inv,
                                  float* __restrict__ comb) {
    long long idx = (long long)blockIdx.x * blockDim.x + threadIdx.x;
    if (idx >= (long long)n * 32) return;
    int e = (int)(idx >> 5), q = (int)(idx & 31);
    int s = edges[e], t = edges[n + e];
    if (s >= num_ops && t < num_ops) {
        float iv = inv[t];
        float4 v = *(const float4*)(mach_c + (size_t)(s - num_ops) * HDIM + q * 4);
        float* dst = comb + (size_t)t * HDIM + q * 4;
        atomicAdd(dst + 0, v.x * iv); atomicAdd(dst + 1, v.y * iv);
        atomicAdd(dst + 2, v.z * iv); atomicAdd(dst + 3, v.w * iv);
    }
}

// ---------------- finalize: x = emb + (cnt ? add/max(cnt,1) : add); LayerNorm; store ----------------
__global__ __launch_bounds__(256) void k_finalize(
    const float* __restrict__ emb, const float* __restrict__ add,
    const float* __restrict__ cnt,
    const float* __restrict__ g, const float* __restrict__ bt,
    float* __restrict__ dst, int M) {
    int wave = threadIdx.x >> 6, lane = threadIdx.x & 63;
    int r = blockIdx.x * 4 + wave;
    if (r >= M) return;
    size_t base = (size_t)r * HDIM;
    int h = lane * 2;
    float2 e = *(const float2*)(emb + base + h);
    float2 a = *(const float2*)(add + base + h);
    float sc = cnt ? (1.f / fmaxf(cnt[r], 1.f)) : 1.f;
    float x0 = e.x + a.x * sc;
    float x1 = e.y + a.y * sc;
    float s = x0 + x1;
#pragma unroll
    for (int o = 32; o; o >>= 1) s += __shfl_xor(s, o);
    float mu = s * (1.f / 128.f);
    float d0 = x0 - mu, d1 = x1 - mu;
    float v = d0 * d0 + d1 * d1;
#pragma unroll
    for (int o = 32; o; o >>= 1) v += __shfl_xor(v, o);
    float inv = rsqrtf(v * (1.f / 128.f) + 1e-5f);
    float y0 = d0 * inv * g[h]     + bt[h];
    float y1 = d1 * inv * g[h + 1] + bt[h + 1];
    *(float2*)(dst + base + h) = make_float2(y0, y1);
}

extern "C" void kernel_launch(void* const* d_in, const int* in_sizes, int n_in,
                              void* d_out, int out_size, void* d_ws, size_t ws_size,
                              hipStream_t stream) {
    const float* op_feat    = (const float*)d_in[0];
    const float* m_feat     = (const float*)d_in[1];
    const int*   prec_e     = (const int*)d_in[2];
    const int*   comp_e     = (const int*)d_in[3];
    const float* op_emb_W   = (const float*)d_in[4];
    const float* op_emb_b   = (const float*)d_in[5];
    const float* mach_emb_W = (const float*)d_in[6];
    const float* mach_emb_b = (const float*)d_in[7];
    const float* prec_W     = (const float*)d_in[8];
    const float* prec_b     = (const float*)d_in[9];
    const float* compat_W   = (const float*)d_in[10];
    const float* compat_b   = (const float*)d_in[11];
    const float* op_ln_g    = (const float*)d_in[12];
    const float* op_ln_b    = (const float*)d_in[13];
    const float* mach_ln_g  = (const float*)d_in[14];
    const float* mach_ln_b  = (const float*)d_in[15];
    float* out = (float*)d_out;

    const int M = NUM_OPS, NM = NUM_MACH;
    const int nprec = in_sizes[2] / 2;
    const int ncomp = in_sizes[3] / 2;

    float* ws = (float*)d_ws;
    size_t o = 0;
    float* op_emb   = ws + o; o += (size_t)M * HDIM;   // 12.8M
    float* op_tc    = ws + o; o += (size_t)M * 256;    // 25.6M
    float* comb     = ws + o; o += (size_t)M * HDIM;   // 12.8M  (pre-scaled prec+compat mean)
    float* mach_sum = ws + o; o += (size_t)NM * HDIM;  // contiguous with comb for one memset
    float* mach_emb = ws + o; o += (size_t)NM * HDIM;
    float* mach_c   = ws + o; o += (size_t)NM * HDIM;
    float* prec_inv = ws + o; o += M;                  // counts -> inverses (contiguous zero region)
    float* op_inv   = ws + o; o += M;
    float* mach_cnt = ws + o; o += NM;

    // ---- counts (edge-structure only) ----
    hipMemsetAsync(prec_inv, 0, (size_t)(M + M + NM) * sizeof(float), stream);
    k_count_prec<<<(nprec + 255) / 256, 256, 0, stream>>>(prec_e + nprec, nprec, prec_inv);
    k_count_compat<<<512, 256, 0, stream>>>(comp_e, ncomp, M, op_inv, mach_cnt);
    k_inv<<<(2 * M + 255) / 256, 256, 0, stream>>>(prec_inv, 2 * M);  // prec_inv & op_inv

    // ---- input embeddings ----
    k_embed<<<(M * HDIM + 255) / 256, 256, 0, stream>>>(op_feat, op_emb_W, op_emb_b, op_emb, M, 6);
    k_embed<<<(NM * HDIM + 255) / 256, 256, 0, stream>>>(m_feat, mach_emb_W, mach_emb_b, mach_emb, NM, 2);

    for (int l = 0; l < 2; ++l) {
        // zero comb + mach_sum (contiguous)
        hipMemsetAsync(comb, 0, ((size_t)M * HDIM + (size_t)NM * HDIM) * sizeof(float), stream);

        k_gemm_dual<<<dim3((M + BM - 1) / BM, 4), 256, 0, stream>>>(
            op_emb, M, prec_W + (size_t)l * HDIM * HDIM, prec_b + (size_t)l * HDIM,
            compat_W + (size_t)l * HDIM * HDIM, compat_b + (size_t)l * HDIM, op_tc);
        k_mach_linear<<<NM, 128, 0, stream>>>(
            mach_emb, compat_W + (size_t)l * HDIM * HDIM, compat_b + (size_t)l * HDIM, mach_c);

        k_scatter_prec<<<(nprec * 32 + 255) / 256, 256, 0, stream>>>(prec_e, nprec, op_tc, prec_inv, comb);
        k_scatter_comp_mach<<<dim3(80, HDIM / MS_H), 256, 0, stream>>>(comp_e, ncomp, M, op_tc, mach_sum);
        k_scatter_comp_op<<<(int)(((long long)ncomp * 32 + 255) / 256), 256, 0, stream>>>(
            comp_e, ncomp, M, mach_c, op_inv, comb);

        int last = (l == 1);
        k_finalize<<<(M + 3) / 4, 256, 0, stream>>>(
            op_emb, comb, nullptr,
            op_ln_g + (size_t)l * HDIM, op_ln_b + (size_t)l * HDIM,
            last ? out : op_emb, M);
        k_finalize<<<NM / 4, 256, 0, stream>>>(
            mach_emb, mach_sum, mach_cnt,
            mach_ln_g + (size_t)l * HDIM, mach_ln_b + (size_t)l * HDIM,
            last ? (out + (size_t)M * HDIM) : mach_emb, NM);
    }
}

// Round 3
// 1325.030 us; speedup vs baseline: 6.6636x; 6.6636x over previous
//
#include <hip/hip_runtime.h>
#include <hip/hip_bf16.h>

#define NUM_OPS   100000
#define NUM_MACH  512
#define HDIM      128
#define P1        100352            // m2o hist offset (98*1024)
#define NHIST     200704            // 196*1024 combined hist size
#define NBLK      196               // scan blocks (1024 elems each)

// ---------------- embedding: out[r,h] = sum_f F[r,f]*W[h,f] + b[h] ----------------
__global__ void k_embed(const float* __restrict__ F,
                        const float* __restrict__ W,
                        const float* __restrict__ b,
                        float* __restrict__ out, int M, int FD) {
    int idx = blockIdx.x * blockDim.x + threadIdx.x;
    if (idx >= M * HDIM) return;
    int r = idx >> 7, h = idx & 127;
    const float* f = F + (size_t)r * FD;
    const float* w = W + (size_t)h * FD;
    float s = b[h];
    for (int i = 0; i < FD; ++i) s += f[i] * w[i];
    out[idx] = s;
}

// ---------------- histogram: prec targets, m2o targets, o2m machine targets ----------------
__global__ void k_hist(const int* __restrict__ prec_e, int nprec,
                       const int* __restrict__ comp_e, int ncomp, int M,
                       int* __restrict__ hist, int* __restrict__ mach_hist) {
    __shared__ int mc[NUM_MACH];
    for (int i = threadIdx.x; i < NUM_MACH; i += blockDim.x) mc[i] = 0;
    __syncthreads();
    int total = nprec + ncomp;
    for (int i = blockIdx.x * blockDim.x + threadIdx.x; i < total; i += gridDim.x * blockDim.x) {
        if (i < nprec) {
            atomicAdd(&hist[prec_e[nprec + i]], 1);
        } else {
            int e = i - nprec;
            int s = comp_e[e], t = comp_e[ncomp + e];
            if (s < M && t >= M) atomicAdd(&mc[t - M], 1);
            else if (s >= M && t < M) atomicAdd(&hist[P1 + t], 1);
        }
    }
    __syncthreads();
    for (int i = threadIdx.x; i < NUM_MACH; i += blockDim.x)
        if (mc[i]) atomicAdd(&mach_hist[i], mc[i]);
}

// ---------------- scan phase 1: per-block sums (1024 ints / block) ----------------
__global__ __launch_bounds__(256) void k_blocksum(const int* __restrict__ hist, int* __restrict__ partial) {
    __shared__ int sh[256];
    int b = blockIdx.x, t = threadIdx.x;
    int4 v = *(const int4*)(hist + b * 1024 + t * 4);
    sh[t] = v.x + v.y + v.z + v.w;
    __syncthreads();
    for (int o = 128; o; o >>= 1) { if (t < o) sh[t] += sh[t + o]; __syncthreads(); }
    if (!t) partial[b] = sh[0];
}

// ---------------- scan phase 2: scan block partials + machine hist (single block) ----------------
__global__ __launch_bounds__(256) void k_scanblock(const int* __restrict__ partial,
                                                   int* __restrict__ block_off,
                                                   const int* __restrict__ mach_hist,
                                                   int* __restrict__ mach_rs,
                                                   int* __restrict__ mach_cur) {
    __shared__ int sh[256];
    int t = threadIdx.x;
    int v = (t < NBLK) ? partial[t] : 0;
    sh[t] = v; __syncthreads();
    for (int o = 1; o < 256; o <<= 1) {
        int x = (t >= o) ? sh[t - o] : 0; __syncthreads();
        sh[t] += x; __syncthreads();
    }
    if (t < NBLK) block_off[t] = sh[t] - v;   // exclusive
    __syncthreads();
    // machine scan (512 counts, 2 per thread)
    int a = mach_hist[2 * t], b = mach_hist[2 * t + 1];
    int pv = a + b;
    sh[t] = pv; __syncthreads();
    for (int o = 1; o < 256; o <<= 1) {
        int x = (t >= o) ? sh[t - o] : 0; __syncthreads();
        sh[t] += x; __syncthreads();
    }
    int excl = sh[t] - pv;
    mach_rs[2 * t] = excl;      mach_rs[2 * t + 1] = excl + a;
    mach_cur[2 * t] = excl;     mach_cur[2 * t + 1] = excl + a;
    if (t == 255) mach_rs[512] = sh[255];
}

// ---------------- scan phase 3: write exclusive row starts + cursors ----------------
__global__ __launch_bounds__(256) void k_scanwrite(const int* __restrict__ hist,
                                                   const int* __restrict__ block_off,
                                                   int* __restrict__ rs, int* __restrict__ cur) {
    __shared__ int sh[256];
    int b = blockIdx.x, t = threadIdx.x;
    int base_i = b * 1024 + t * 4;
    int4 v = *(const int4*)(hist + base_i);
    int tsum = v.x + v.y + v.z + v.w;
    sh[t] = tsum; __syncthreads();
    for (int o = 1; o < 256; o <<= 1) {
        int x = (t >= o) ? sh[t - o] : 0; __syncthreads();
        sh[t] += x; __syncthreads();
    }
    int off = block_off[b] + sh[t] - tsum;
    int4 r; r.x = off; r.y = off + v.x; r.z = off + v.x + v.y; r.w = off + v.x + v.y + v.z;
    *(int4*)(rs + base_i) = r;
    *(int4*)(cur + base_i) = r;
}

// ---------------- bucket fill ----------------
__global__ void k_fill(const int* __restrict__ prec_e, int nprec,
                       const int* __restrict__ comp_e, int ncomp, int M,
                       int* __restrict__ cur, int* __restrict__ mach_cur,
                       int* __restrict__ bucket_all, int* __restrict__ bucket_mach) {
    int i = blockIdx.x * blockDim.x + threadIdx.x;
    int total = nprec + ncomp;
    if (i >= total) return;
    if (i < nprec) {
        int s = prec_e[i], t = prec_e[nprec + i];
        int pos = atomicAdd(&cur[t], 1);
        bucket_all[pos] = s;
    } else {
        int e = i - nprec;
        int s = comp_e[e], t = comp_e[ncomp + e];
        if (s < M && t >= M)      { int pos = atomicAdd(&mach_cur[t - M], 1); bucket_mach[pos] = s; }
        else if (s >= M && t < M) { int pos = atomicAdd(&cur[P1 + t], 1);     bucket_all[pos] = s - M; }
    }
}

// ---------------- fused dual GEMM: Y[m, 0:128]=X@Wa^T+ba, Y[m,128:256]=X@Wb^T+bb ----------------
#define BM 64
#define BK 16
__global__ __launch_bounds__(256) void k_gemm_dual(
    const float* __restrict__ X, int M,
    const float* __restrict__ Wa, const float* __restrict__ ba,
    const float* __restrict__ Wb, const float* __restrict__ bb,
    float* __restrict__ Y) {
    __shared__ float As[BK][BM + 4];
    __shared__ float Bs[BK][BM + 4];
    int by = blockIdx.y;
    int m0 = blockIdx.x * BM;
    const float* W; const float* bias; int n0;
    if (by < 2) { W = Wa; bias = ba; n0 = by * 64; }
    else        { W = Wb; bias = bb; n0 = (by - 2) * 64; }
    int colbase = (by < 2 ? 0 : 128) + n0;

    int t  = threadIdx.x;
    int tx = t & 15, ty = t >> 4;
    float acc[4][4] = {};

    for (int k0 = 0; k0 < HDIM; k0 += BK) {
        {
            int m = t >> 2, k = (t & 3) * 4;
            int gm = m0 + m;
            float4 v = make_float4(0.f, 0.f, 0.f, 0.f);
            if (gm < M) v = *(const float4*)(X + (size_t)gm * HDIM + k0 + k);
            As[k + 0][m] = v.x; As[k + 1][m] = v.y; As[k + 2][m] = v.z; As[k + 3][m] = v.w;
        }
        {
            int n = t >> 2, k = (t & 3) * 4;
            float4 v = *(const float4*)(W + (size_t)(n0 + n) * HDIM + k0 + k);
            Bs[k + 0][n] = v.x; Bs[k + 1][n] = v.y; Bs[k + 2][n] = v.z; Bs[k + 3][n] = v.w;
        }
        __syncthreads();
#pragma unroll
        for (int kk = 0; kk < BK; ++kk) {
            const float4 a = *(const float4*)&As[kk][ty * 4];
            const float4 b = *(const float4*)&Bs[kk][tx * 4];
            acc[0][0] += a.x * b.x; acc[0][1] += a.x * b.y; acc[0][2] += a.x * b.z; acc[0][3] += a.x * b.w;
            acc[1][0] += a.y * b.x; acc[1][1] += a.y * b.y; acc[1][2] += a.y * b.z; acc[1][3] += a.y * b.w;
            acc[2][0] += a.z * b.x; acc[2][1] += a.z * b.y; acc[2][2] += a.z * b.z; acc[2][3] += a.z * b.w;
            acc[3][0] += a.w * b.x; acc[3][1] += a.w * b.y; acc[3][2] += a.w * b.z; acc[3][3] += a.w * b.w;
        }
        __syncthreads();
    }
    float bx = bias[n0 + tx * 4 + 0];
    float by2 = bias[n0 + tx * 4 + 1];
    float bz = bias[n0 + tx * 4 + 2];
    float bw = bias[n0 + tx * 4 + 3];
#pragma unroll
    for (int i = 0; i < 4; ++i) {
        int gm = m0 + ty * 4 + i;
        if (gm < M) {
            float4 o = make_float4(acc[i][0] + bx, acc[i][1] + by2, acc[i][2] + bz, acc[i][3] + bw);
            *(float4*)(Y + (size_t)gm * 256 + colbase + tx * 4) = o;
        }
    }
}

// ---------------- machine linear: Y = X @ W^T + b ----------------
__global__ __launch_bounds__(128) void k_mach_linear(
    const float* __restrict__ X, const float* __restrict__ W,
    const float* __restrict__ b, float* __restrict__ Y) {
    __shared__ float row[HDIM];
    int r = blockIdx.x, t = threadIdx.x;
    row[t] = X[(size_t)r * HDIM + t];
    __syncthreads();
    const float* w = W + (size_t)t * HDIM;
    float s = b[t];
#pragma unroll 8
    for (int k = 0; k < HDIM; ++k) s += row[k] * w[k];
    Y[(size_t)r * HDIM + t] = s;
}

// ---------------- fused op update: gather prec + gather m2o + emb + LN ----------------
__global__ __launch_bounds__(256) void k_op_fused(
    const float* __restrict__ op_emb, const float* __restrict__ op_tc,
    const float* __restrict__ mach_c,
    const int* __restrict__ rs, const int* __restrict__ bucket_all,
    const float* __restrict__ g, const float* __restrict__ bt,
    float* __restrict__ dst, int M) {
    int wave = threadIdx.x >> 6, lane = threadIdx.x & 63;
    int r = blockIdx.x * 4 + wave;
    if (r >= M) return;
    int h = lane * 2;

    float a0 = 0.f, a1 = 0.f;
    int s0 = rs[r], e0 = rs[r + 1];
    for (int j = s0; j < e0; ++j) {
        int s = __builtin_amdgcn_readfirstlane(bucket_all[j]);
        float2 v = *(const float2*)(op_tc + (size_t)s * 256 + h);
        a0 += v.x; a1 += v.y;
    }
    float pinv = 1.f / fmaxf((float)(e0 - s0), 1.f);

    float b0 = 0.f, b1 = 0.f;
    int s1 = rs[P1 + r], e1 = rs[P1 + r + 1];
    for (int j = s1; j < e1; ++j) {
        int m = __builtin_amdgcn_readfirstlane(bucket_all[j]);
        float2 v = *(const float2*)(mach_c + m * HDIM + h);
        b0 += v.x; b1 += v.y;
    }
    float cinv = 1.f / fmaxf((float)(e1 - s1), 1.f);

    float2 e = *(const float2*)(op_emb + (size_t)r * HDIM + h);
    float x0 = e.x + a0 * pinv + b0 * cinv;
    float x1 = e.y + a1 * pinv + b1 * cinv;

    float s = x0 + x1;
#pragma unroll
    for (int o = 32; o; o >>= 1) s += __shfl_xor(s, o);
    float mu = s * (1.f / 128.f);
    float d0 = x0 - mu, d1 = x1 - mu;
    float v2 = d0 * d0 + d1 * d1;
#pragma unroll
    for (int o = 32; o; o >>= 1) v2 += __shfl_xor(v2, o);
    float inv = rsqrtf(v2 * (1.f / 128.f) + 1e-5f);
    float2 gg = *(const float2*)(g + h);
    float2 bb = *(const float2*)(bt + h);
    float2 out = make_float2(d0 * inv * gg.x + bb.x, d1 * inv * gg.y + bb.y);
    *(float2*)(dst + (size_t)r * HDIM + h) = out;
}

// ---------------- machine gather: partial sums per (machine, slice) ----------------
__global__ __launch_bounds__(256) void k_mach_gather(
    const int* __restrict__ mach_rs, const int* __restrict__ bucket_mach,
    const float* __restrict__ op_tc, float* __restrict__ mach_sum) {
    int m = blockIdx.x;
    int h = threadIdx.x & 127;
    int slot = threadIdx.x >> 7;   // 0..1
    int slice = blockIdx.y;        // 0..7
    int s0 = mach_rs[m], e0 = mach_rs[m + 1];
    float acc = 0.f;
    for (int j = s0 + slice * 2 + slot; j < e0; j += 16) {
        int s = __builtin_amdgcn_readfirstlane(bucket_mach[j]);
        acc += op_tc[(size_t)s * 256 + 128 + h];
    }
    if (acc != 0.f) atomicAdd(&mach_sum[m * HDIM + h], acc);
}

// ---------------- machine finalize: mean + emb + LN ----------------
__global__ __launch_bounds__(256) void k_mach_fin(
    const float* __restrict__ mach_emb, const float* __restrict__ mach_sum,
    const int* __restrict__ mach_rs,
    const float* __restrict__ g, const float* __restrict__ bt,
    float* __restrict__ dst) {
    int wave = threadIdx.x >> 6, lane = threadIdx.x & 63;
    int m = blockIdx.x * 4 + wave;
    int h = lane * 2;
    float sc = 1.f / fmaxf((float)(mach_rs[m + 1] - mach_rs[m]), 1.f);
    float2 e = *(const float2*)(mach_emb + m * HDIM + h);
    float2 a = *(const float2*)(mach_sum + m * HDIM + h);
    float x0 = e.x + a.x * sc;
    float x1 = e.y + a.y * sc;
    float s = x0 + x1;
#pragma unroll
    for (int o = 32; o; o >>= 1) s += __shfl_xor(s, o);
    float mu = s * (1.f / 128.f);
    float d0 = x0 - mu, d1 = x1 - mu;
    float v2 = d0 * d0 + d1 * d1;
#pragma unroll
    for (int o = 32; o; o >>= 1) v2 += __shfl_xor(v2, o);
    float inv = rsqrtf(v2 * (1.f / 128.f) + 1e-5f);
    float2 gg = *(const float2*)(g + h);
    float2 bb = *(const float2*)(bt + h);
    *(float2*)(dst + m * HDIM + h) =
        make_float2(d0 * inv * gg.x + bb.x, d1 * inv * gg.y + bb.y);
}

extern "C" void kernel_launch(void* const* d_in, const int* in_sizes, int n_in,
                              void* d_out, int out_size, void* d_ws, size_t ws_size,
                              hipStream_t stream) {
    const float* op_feat    = (const float*)d_in[0];
    const float* m_feat     = (const float*)d_in[1];
    const int*   prec_e     = (const int*)d_in[2];
    const int*   comp_e     = (const int*)d_in[3];
    const float* op_emb_W   = (const float*)d_in[4];
    const float* op_emb_b   = (const float*)d_in[5];
    const float* mach_emb_W = (const float*)d_in[6];
    const float* mach_emb_b = (const float*)d_in[7];
    const float* prec_W     = (const float*)d_in[8];
    const float* prec_b     = (const float*)d_in[9];
    const float* compat_W   = (const float*)d_in[10];
    const float* compat_b   = (const float*)d_in[11];
    const float* op_ln_g    = (const float*)d_in[12];
    const float* op_ln_b    = (const float*)d_in[13];
    const float* mach_ln_g  = (const float*)d_in[14];
    const float* mach_ln_b  = (const float*)d_in[15];
    float* out = (float*)d_out;

    const int M = NUM_OPS, NM = NUM_MACH;
    const int nprec = in_sizes[2] / 2;
    const int ncomp = in_sizes[3] / 2;

    float* ws = (float*)d_ws;
    size_t o = 0;
    float* op_emb   = ws + o; o += (size_t)M * HDIM;   // 12.8M
    float* op_tc    = ws + o; o += (size_t)M * 256;    // 25.6M
    float* mach_emb = ws + o; o += (size_t)NM * HDIM;
    float* mach_c   = ws + o; o += (size_t)NM * HDIM;
    float* mach_sum = ws + o; o += (size_t)NM * HDIM;
    int* ip = (int*)(ws + o);
    size_t io = 0;
    int* hist      = ip + io; io += NHIST;
    int* mach_hist = ip + io; io += 512;       // contiguous with hist for one memset
    int* rs        = ip + io; io += NHIST;
    int* cur       = ip + io; io += NHIST;
    int* mach_rs   = ip + io; io += 520;
    int* mach_cur  = ip + io; io += 512;
    int* partial   = ip + io; io += 256;
    int* block_off = ip + io; io += 256;
    int* bucket_all  = ip + io; io += (size_t)nprec + ncomp;
    int* bucket_mach = ip + io; io += (size_t)ncomp;

    // ---- CSR build ----
    hipMemsetAsync(hist, 0, (size_t)(NHIST + 512) * sizeof(int), stream);
    k_hist<<<1024, 256, 0, stream>>>(prec_e, nprec, comp_e, ncomp, M, hist, mach_hist);
    k_blocksum<<<NBLK, 256, 0, stream>>>(hist, partial);
    k_scanblock<<<1, 256, 0, stream>>>(partial, block_off, mach_hist, mach_rs, mach_cur);
    k_scanwrite<<<NBLK, 256, 0, stream>>>(hist, block_off, rs, cur);
    k_fill<<<(nprec + ncomp + 255) / 256, 256, 0, stream>>>(
        prec_e, nprec, comp_e, ncomp, M, cur, mach_cur, bucket_all, bucket_mach);

    // ---- input embeddings ----
    k_embed<<<(M * HDIM + 255) / 256, 256, 0, stream>>>(op_feat, op_emb_W, op_emb_b, op_emb, M, 6);
    k_embed<<<(NM * HDIM + 255) / 256, 256, 0, stream>>>(m_feat, mach_emb_W, mach_emb_b, mach_emb, NM, 2);

    for (int l = 0; l < 2; ++l) {
        int last = (l == 1);
        hipMemsetAsync(mach_sum, 0, (size_t)NM * HDIM * sizeof(float), stream);

        k_gemm_dual<<<dim3((M + BM - 1) / BM, 4), 256, 0, stream>>>(
            op_emb, M, prec_W + (size_t)l * HDIM * HDIM, prec_b + (size_t)l * HDIM,
            compat_W + (size_t)l * HDIM * HDIM, compat_b + (size_t)l * HDIM, op_tc);
        k_mach_linear<<<NM, 128, 0, stream>>>(
            mach_emb, compat_W + (size_t)l * HDIM * HDIM, compat_b + (size_t)l * HDIM, mach_c);

        k_op_fused<<<(M + 3) / 4, 256, 0, stream>>>(
            op_emb, op_tc, mach_c, rs, bucket_all,
            op_ln_g + (size_t)l * HDIM, op_ln_b + (size_t)l * HDIM,
            last ? out : op_emb, M);

        k_mach_gather<<<dim3(NM, 8), 256, 0, stream>>>(mach_rs, bucket_mach, op_tc, mach_sum);
        k_mach_fin<<<NM / 4, 256, 0, stream>>>(
            mach_emb, mach_sum, mach_rs,
            mach_ln_g + (size_t)l * HDIM, mach_ln_b + (size_t)l * HDIM,
            last ? (out + (size_t)M * HDIM) : mach_emb);
    }
}